// Round 8
// baseline (522.403 us; speedup 1.0000x reference)
//
#include <hip/hip_runtime.h>
#include <hip/hip_bf16.h>
#include <cmath>

// Problem constants
constexpr int Bc = 2, Tc = 4096, Dc = 2048, Hc = 16, HDc = 128;
constexpr int Mrows = Bc * Tc;            // 8192
constexpr int NCHUNK = 32, CHUNK = 128;   // T = NCHUNK * CHUNK

// ---------- small helpers ----------
__device__ __forceinline__ unsigned short f2bf(float x) {
  union { float f; unsigned int u; } v; v.f = x;
  unsigned int r = v.u + 0x7FFFu + ((v.u >> 16) & 1u);  // RNE
  return (unsigned short)(r >> 16);
}
__device__ __forceinline__ float bf2f(unsigned short u) {
  union { unsigned int i; float f; } v; v.i = ((unsigned int)u) << 16;
  return v.f;
}

typedef __attribute__((ext_vector_type(8))) short bf16x8;
typedef __attribute__((ext_vector_type(4))) float f32x4;

__device__ __forceinline__ void gload16(const unsigned short* g, unsigned short* l) {
  __builtin_amdgcn_global_load_lds(
      (const __attribute__((address_space(1))) void*)(const void*)g,
      (__attribute__((address_space(3))) void*)(void*)l,
      16, 0, 0);
}

template <int N>
__device__ __forceinline__ void waitcnt_vm() {
  if constexpr (N == 8)       asm volatile("s_waitcnt vmcnt(8)" ::: "memory");
  else if constexpr (N == 16) asm volatile("s_waitcnt vmcnt(16)" ::: "memory");
  else                        asm volatile("s_waitcnt vmcnt(0)" ::: "memory");
}

// ---------- fp32 -> bf16 convert (vectorized; z-batched over 2 buffers) ----------
__global__ void cvt_bf16(const float* __restrict__ in, unsigned short* __restrict__ outp) {
  size_t i = ((size_t)blockIdx.x * 256 + threadIdx.x) * 4;
  float4 f = *(const float4*)(in + i);
  ushort4 u;
  u.x = f2bf(f.x); u.y = f2bf(f.y); u.z = f2bf(f.z); u.w = f2bf(f.w);
  *(ushort4*)(outp + i) = u;
}

__global__ void cvt_bf16_2(const float* __restrict__ in0, unsigned short* __restrict__ out0,
                           const float* __restrict__ in1, unsigned short* __restrict__ out1) {
  const float* in = blockIdx.y ? in1 : in0;
  unsigned short* op = blockIdx.y ? out1 : out0;
  size_t i = ((size_t)blockIdx.x * 256 + threadIdx.x) * 4;
  float4 f = *(const float4*)(in + i);
  ushort4 u;
  u.x = f2bf(f.x); u.y = f2bf(f.y); u.z = f2bf(f.z); u.w = f2bf(f.w);
  *(ushort4*)(op + i) = u;
}

// ---------- W [K][N] fp32 -> Wt [N][K] bf16, z-batched over 4 matrices ----------
__global__ void transpose_cvt4(const float* __restrict__ W0, unsigned short* __restrict__ T0,
                               const float* __restrict__ W1, unsigned short* __restrict__ T1,
                               const float* __restrict__ W2, unsigned short* __restrict__ T2,
                               const float* __restrict__ W3, unsigned short* __restrict__ T3) {
  const float* W; unsigned short* Wt;
  switch (blockIdx.z) {
    case 0: W = W0; Wt = T0; break;
    case 1: W = W1; Wt = T1; break;
    case 2: W = W2; Wt = T2; break;
    default: W = W3; Wt = T3; break;
  }
  __shared__ float tile[32][33];
  int n0 = blockIdx.x * 32, k0 = blockIdx.y * 32;
  int tx = threadIdx.x & 31, ty = threadIdx.x >> 5;  // ty: 0..7
#pragma unroll
  for (int i = 0; i < 4; ++i)
    tile[ty + 8 * i][tx] = W[(size_t)(k0 + ty + 8 * i) * Dc + n0 + tx];
  __syncthreads();
#pragma unroll
  for (int i = 0; i < 4; ++i)
    Wt[(size_t)(n0 + ty + 8 * i) * Dc + k0 + tx] = f2bf(tile[tx][ty + 8 * i]);
}

// ============================================================================
// Barrier-light ring-4 GEMM: C[M,N] = A[M,K](bf16, lda) * Bt[N,K](bf16)^T
// K hardcoded 2048, BK=32 K-tiles. LDS ring of 4 (A-slab + B-slab) buffers,
// staged 3 tiles ahead via global_load_lds. ONE counted vmcnt + ONE s_barrier
// per K-tile; compiler emits fine-grained lgkmcnt so ds_read ∥ MFMA.
// R8 geometry: wave tile 128x128 (MI=NI=8) -> per-FLOP LDS reads cut 1.5x
// (LDS cap 62% -> 83%); 4 waves/block, 1 wave/SIMD (acc=256 VGPR).
// XOR bank-conflict swizzle (verified 0 conflicts): pre-swizzled global
// source for staging (LDS dest linear) + swizzle folded into per-lane reads.
// EPI: 0 = fp32 store, 1 = bf16 store,
//      3 = fused QKV (N=6144, BN=256): seg0->exp->C0, seg1->exp->C1, seg2->C2
// z-batch: blockIdx.y==1 switches to (A1,B1,C1a) (weight-pair use).
// ============================================================================
template <int EPI, int WMw, int WNw, int MI, int NI>
__global__ __launch_bounds__(WMw * WNw * 64, (MI * NI >= 64) ? 1 : 2) void gemmL(
    const unsigned short* __restrict__ A0, const unsigned short* __restrict__ B0,
    void* __restrict__ C0, void* __restrict__ C1, void* __restrict__ C2,
    const unsigned short* __restrict__ A1, const unsigned short* __restrict__ B1,
    void* __restrict__ C1a,
    int M, int N, int lda, int ldc, float eoff) {
  constexpr int K = 2048;
  constexpr int NT = K / 32;                 // 64 K-tiles
  constexpr int THREADS = WMw * WNw * 64;
  constexpr int BM = WMw * MI * 16;
  constexpr int BN = WNw * NI * 16;
  constexpr int ASLAB = BM * 32;             // elems per A K-slab
  constexpr int BSLAB = BN * 32;
  constexpr int BUF = ASLAB + BSLAB;
  constexpr int SROWS = THREADS / 4;         // rows staged per gload pass
  constexpr int APASS = BM / SROWS;          // gload passes per A slab
  constexpr int BPASS = BN / SROWS;
  constexpr int LPT = APASS + BPASS;         // loads per tile
  static_assert(BM % SROWS == 0 && BN % SROWS == 0, "staging geometry");
  extern __shared__ unsigned short lds[];    // 4 * BUF elems

  const unsigned short* A = A0;
  const unsigned short* Bt = B0;
  void* Cz = C0;
  if (blockIdx.y) { A = A1; Bt = B1; Cz = C1a; }

  const int tid = threadIdx.x;
  const int lane = tid & 63;
  const int wave = tid >> 6;
  const int wm = wave / WNw;
  const int wn = wave % WNw;

  const int nbn = N / BN;
  const int nwg = (M / BM) * nbn;
  const int bidx = (int)blockIdx.x;
  const int wgid = (bidx & 7) * (nwg >> 3) + (bidx >> 3);  // XCD swizzle (nwg%8==0)
  const int bm = wgid / nbn;
  const int bn = wgid % nbn;

  // ---- staging: slab = rows x 32 bf16 (64B rows), APASS/BPASS gloads per slab
  const int srow = tid >> 2;                    // 0..SROWS-1
  const int scolL = (tid & 3) << 3;             // linear LDS col (elems)
  const int scolG = scolL ^ ((srow & 6) << 2);  // pre-swizzled global source col
  const unsigned short* gA = A + (size_t)(bm * BM + srow) * lda + scolG;
  const unsigned short* gB = Bt + (size_t)(bn * BN + srow) * K + scolG;
  const int sstage = srow * 32 + scolL;         // LDS elem offset (linear dest)
  const size_t arstep = (size_t)SROWS * lda;
  const size_t brstep = (size_t)SROWS * K;

  // ---- fragment read offsets (swizzle folded per-lane)
  const int fr = lane & 15;
  const int fko = ((lane >> 4) << 3) ^ ((lane & 6) << 2);
  const int aoff = (wm * MI * 16 + fr) * 32 + fko;            // + mi*512
  const int boff = ASLAB + (wn * NI * 16 + fr) * 32 + fko;    // + ni*512

  f32x4 acc[MI][NI] = {};

  // ---- prologue: stage tiles 0,1,2 into slots 0,1,2
#pragma unroll
  for (int t = 0; t < 3; ++t) {
    const unsigned short* sA = gA + t * 32;
    const unsigned short* sB = gB + t * 32;
    unsigned short* dst = lds + t * BUF;
#pragma unroll
    for (int p = 0; p < APASS; ++p)
      gload16(sA + p * arstep, dst + sstage + p * SROWS * 32);
#pragma unroll
    for (int p = 0; p < BPASS; ++p)
      gload16(sB + p * brstep, dst + ASLAB + sstage + p * SROWS * 32);
  }
  waitcnt_vm<2 * LPT>();  // tile 0 landed
  __builtin_amdgcn_s_barrier();

  for (int v = 0; v < NT; ++v) {
    const int rb = (v & 3) * BUF;            // read slot
    const int wb = ((v + 3) & 3) * BUF;      // stage slot (tile v+3)
    const int tn = (v + 3) & (NT - 1);       // wrap-stage near tail: harmless
    const unsigned short* srcA = gA + tn * 32;
    const unsigned short* srcB = gB + tn * 32;

    // ds_reads for tile v (compiler inserts fine-grained lgkmcnt before MFMA)
    bf16x8 af[MI], bfv[NI];
#pragma unroll
    for (int mi = 0; mi < MI; ++mi)
      af[mi] = *(const bf16x8*)(lds + rb + aoff + mi * 512);
#pragma unroll
    for (int ni = 0; ni < NI; ++ni)
      bfv[ni] = *(const bf16x8*)(lds + rb + boff + ni * 512);

    // stage tile v+3
#pragma unroll
    for (int p = 0; p < APASS; ++p)
      gload16(srcA + p * arstep, lds + wb + sstage + p * SROWS * 32);
#pragma unroll
    for (int p = 0; p < BPASS; ++p)
      gload16(srcB + p * brstep, lds + wb + ASLAB + sstage + p * SROWS * 32);

    // MFMA cluster
    __builtin_amdgcn_s_setprio(1);
#pragma unroll
    for (int mi = 0; mi < MI; ++mi)
#pragma unroll
      for (int ni = 0; ni < NI; ++ni)
        acc[mi][ni] = __builtin_amdgcn_mfma_f32_16x16x32_bf16(af[mi], bfv[ni], acc[mi][ni], 0, 0, 0);
    __builtin_amdgcn_s_setprio(0);

    // one counted wait + one barrier per tile: tile v+1 landed for all waves
    waitcnt_vm<2 * LPT>();
    __builtin_amdgcn_s_barrier();
  }

  // ---- epilogue
  const int fq = lane >> 4;
  const int crow = bm * BM + wm * (MI * 16);
  if constexpr (EPI == 3) {
    const int seg = bn >> 3;  // 0:Q 1:K 2:V   (BN=256, 8 col-blocks/segment)
    unsigned short* outp = (unsigned short*)(seg == 0 ? C0 : (seg == 1 ? C1 : C2));
    const int ccol = (bn & 7) * BN + wn * (NI * 16) + fr;
#pragma unroll
    for (int mi = 0; mi < MI; ++mi)
#pragma unroll
      for (int ni = 0; ni < NI; ++ni)
#pragma unroll
        for (int ii = 0; ii < 4; ++ii) {
          const int r = crow + mi * 16 + fq * 4 + ii;
          const int c = ccol + ni * 16;
          float vv = acc[mi][ni][ii];
          if (seg < 2) vv = __expf(vv + eoff);
          outp[(size_t)r * ldc + c] = f2bf(vv);
        }
  } else {
    const int ccol = bn * BN + wn * (NI * 16) + fr;
#pragma unroll
    for (int mi = 0; mi < MI; ++mi)
#pragma unroll
      for (int ni = 0; ni < NI; ++ni)
#pragma unroll
        for (int ii = 0; ii < 4; ++ii) {
          const int r = crow + mi * 16 + fq * 4 + ii;
          const int c = ccol + ni * 16;
          const size_t idx = (size_t)r * ldc + c;
          float vv = acc[mi][ni][ii];
          if (EPI == 0) ((float*)Cz)[idx] = vv;
          else          ((unsigned short*)Cz)[idx] = f2bf(vv);
        }
  }
}

// ---------- fused dot + chunk-sum: per (bh, chunk) block ----------
__global__ void dot_chunks(const unsigned short* __restrict__ qp,
                           const unsigned short* __restrict__ kp,
                           const unsigned short* __restrict__ v,
                           float* __restrict__ dotb,
                           float* __restrict__ chks) {
  __shared__ float dt[CHUNK];
  const int bid = blockIdx.x;          // bh*NCHUNK + c
  const int c = bid & (NCHUNK - 1);
  const int bh = bid >> 5;
  const int b = bh >> 4, h = bh & 15;
  const int tid = threadIdx.x;         // 256
  const int lane = tid & 63, wv = tid >> 6;
  const int qw = lane >> 4, j = lane & 15;
  const int t0 = c * CHUNK;

#pragma unroll
  for (int pass = 0; pass < 8; ++pass) {
    const int tl = pass * 16 + wv * 4 + qw;   // 0..127
    const int t = t0 + tl;
    const size_t base = ((size_t)(b * Tc + t)) * Dc + h * HDc + j * 8;
    bf16x8 q = *(const bf16x8*)(qp + base);
    bf16x8 k = *(const bf16x8*)(kp + base);
    float p = 0.f;
#pragma unroll
    for (int i = 0; i < 8; ++i)
      p += bf2f((unsigned short)q[i]) * bf2f((unsigned short)k[i]);
#pragma unroll
    for (int m = 8; m; m >>= 1) p += __shfl_xor(p, m);
    if (j == 0) {
      dt[tl] = p;
      dotb[(size_t)bh * Tc + t] = p;
    }
  }
  __syncthreads();
  if (tid < HDc) {
    const int d = tid;
    const unsigned short* vp = v + ((size_t)(b * Tc + t0)) * Dc + h * HDc + d;
    float acc = 0.f;
    for (int t = 0; t < CHUNK; ++t)
      acc += dt[t] * bf2f(vp[(size_t)t * Dc]);
    chks[(size_t)bid * HDc + d] = acc;
  }
}

// ---------- chunked scan: pass 2 (exclusive scan of chunk sums) ----------
__global__ void scan_offsets(float* __restrict__ chks) {
  int bh = blockIdx.x;
  int d = threadIdx.x;
  float run = 0.f;
  for (int c = 0; c < NCHUNK; ++c) {
    size_t idx = ((size_t)bh * NCHUNK + c) * HDc + d;
    float tmp = chks[idx];
    chks[idx] = run;
    run += tmp;
  }
}

// ---------- chunked scan: pass 3 (final prefix + divide by kp, bf16 out) ----------
__global__ void scan_final(const float* __restrict__ dotb,
                           const unsigned short* __restrict__ v,
                           const unsigned short* __restrict__ kp,
                           const float* __restrict__ chks,
                           unsigned short* __restrict__ attn) {
  int bid = blockIdx.x;
  int c = bid % NCHUNK, bh = bid / NCHUNK;
  int b = bh / Hc, h = bh % Hc;
  int d = threadIdx.x;
  const float* dp = dotb + (size_t)bh * Tc + c * CHUNK;
  size_t base = ((size_t)(b * Tc + c * CHUNK)) * Dc + h * HDc + d;
  float acc = chks[(size_t)bid * HDc + d];
  for (int t = 0; t < CHUNK; ++t) {
    size_t idx = base + (size_t)t * Dc;
    acc += dp[t] * bf2f(v[idx]);
    attn[idx] = f2bf(acc / bf2f(kp[idx]));
  }
}

// ---------- launch ----------
extern "C" void kernel_launch(void* const* d_in, const int* in_sizes, int n_in,
                              void* d_out, int out_size, void* d_ws, size_t ws_size,
                              hipStream_t stream) {
  const float* hs = (const float*)d_in[0];
  const float* Wq = (const float*)d_in[1];
  const float* Wk = (const float*)d_in[2];
  const float* Wv = (const float*)d_in[3];
  const float* Wo = (const float*)d_in[4];
  const float* Fq = (const float*)d_in[5];
  const float* Fk = (const float*)d_in[6];
  float* out = (float*)d_out;

  const size_t MD = (size_t)Mrows * Dc;  // 16,777,216
  const size_t DD = (size_t)Dc * Dc;     // 4,194,304 (MD == 4*DD)

  char* w = (char*)d_ws;
  size_t off = 0;
  auto take = [&](size_t bytes) -> void* {
    void* r = w + off;
    off += (bytes + 255) & ~(size_t)255;
    return r;
  };

  unsigned short* hs_bf = (unsigned short*)take(MD * 2);  // reused as attnbf
  unsigned short* wq_bf = (unsigned short*)take(DD * 2);  // these 4 reused as Qp
  unsigned short* wtfq  = (unsigned short*)take(DD * 2);
  unsigned short* wk_bf = (unsigned short*)take(DD * 2);
  unsigned short* wtfk  = (unsigned short*)take(DD * 2);
  unsigned short* wcat  = (unsigned short*)take(3 * DD * 2);  // [Wqf^T|Wkf^T|Wv^T]
  unsigned short* wto   = (unsigned short*)take(DD * 2);
  unsigned short* Kp    = (unsigned short*)take(MD * 2);
  unsigned short* Vbf   = (unsigned short*)take(MD * 2);
  float* dotb = (float*)take((size_t)Bc * Hc * Tc * 4);
  float* chks = (float*)take((size_t)Bc * Hc * NCHUNK * HDc * 4);

  // aliases (stream-ordered reuse)
  unsigned short* Qp = wq_bf;        // over the 4 dead weight buffers (4*DD == MD)
  unsigned short* attnbf = hs_bf;    // hs_bf dead after fused QKV GEMM

  const float OFF = (float)(-0.5 * log(2048.0) + 1e-6);

  // allow dynamic LDS (defensive; ignore errors)
  (void)hipFuncSetAttribute((const void*)gemmL<0, 2, 2, 8, 8>, hipFuncAttributeMaxDynamicSharedMemorySize, 131072);
  (void)hipFuncSetAttribute((const void*)gemmL<3, 2, 2, 8, 8>, hipFuncAttributeMaxDynamicSharedMemorySize, 131072);
  (void)hipFuncSetAttribute((const void*)gemmL<1, 2, 2, 4, 4>, hipFuncAttributeMaxDynamicSharedMemorySize, 65536);

  // 1) convert activations + plain-layout Wq, Wk
  cvt_bf16<<<(int)(MD / 1024), 256, 0, stream>>>(hs, hs_bf);
  cvt_bf16_2<<<dim3((int)(DD / 1024), 2), 256, 0, stream>>>(Wq, wq_bf, Wk, wk_bf);

  // 2) transpose+convert Fq, Fk, Wv, Wo (one z-batched dispatch)
  transpose_cvt4<<<dim3(Dc / 32, Dc / 32, 4), 256, 0, stream>>>(
      Fq, wtfq, Fk, wtfk, Wv, wcat + 2 * DD, Wo, wto);

  // 3) weight products (z-batched, 128^2 tiles, ring-4 = 64KB LDS):
  //    wcat[0:DD) = Fq^T @ Wq^T = (Wq@Fq)^T ; wcat[DD:2DD) same for K
  gemmL<1, 2, 2, 4, 4><<<dim3(256, 2), 256, 65536, stream>>>(
      wtfq, wq_bf, wcat, nullptr, nullptr,
      wtfk, wk_bf, wcat + DD,
      2048, 2048, 2048, 2048, 0.f);

  // 4) fused QKV GEMM: hs @ [Wqf|Wkf|Wv], epilogue exp/exp/plain -> Qp,Kp,Vbf
  const int fblocks = (Mrows / 256) * (6144 / 256);  // 768
  gemmL<3, 2, 2, 8, 8><<<fblocks, 256, 131072, stream>>>(
      hs_bf, wcat, Qp, Kp, Vbf, nullptr, nullptr, nullptr,
      Mrows, 6144, Dc, Dc, OFF);

  // 5) fused per-position dot + chunk sums
  dot_chunks<<<Bc * Hc * NCHUNK, 256, 0, stream>>>(Qp, Kp, Vbf, dotb, chks);

  // 6) exclusive scan of chunk sums + final prefix/divide
  scan_offsets<<<Bc * Hc, 128, 0, stream>>>(chks);
  scan_final<<<Bc * Hc * NCHUNK, 128, 0, stream>>>(dotb, Vbf, Kp, chks, attnbf);

  // 7) output projection (fp32 out)
  const int gblocks = (Mrows / 256) * (Dc / 256);  // 256
  gemmL<0, 2, 2, 8, 8><<<gblocks, 256, 131072, stream>>>(
      attnbf, wto, out, nullptr, nullptr, nullptr, nullptr, nullptr,
      Mrows, Dc, Dc, Dc, 0.f);
}

// Round 9
// 450.799 us; speedup vs baseline: 1.1588x; 1.1588x over previous
//
#include <hip/hip_runtime.h>
#include <hip/hip_bf16.h>
#include <cmath>

// Problem constants
constexpr int Bc = 2, Tc = 4096, Dc = 2048, Hc = 16, HDc = 128;
constexpr int Mrows = Bc * Tc;            // 8192
constexpr int NCHUNK = 32, CHUNK = 128;   // T = NCHUNK * CHUNK

// ---------- small helpers ----------
__device__ __forceinline__ unsigned short f2bf(float x) {
  union { float f; unsigned int u; } v; v.f = x;
  unsigned int r = v.u + 0x7FFFu + ((v.u >> 16) & 1u);  // RNE
  return (unsigned short)(r >> 16);
}
__device__ __forceinline__ float bf2f(unsigned short u) {
  union { unsigned int i; float f; } v; v.i = ((unsigned int)u) << 16;
  return v.f;
}

typedef __attribute__((ext_vector_type(8))) short bf16x8;
typedef __attribute__((ext_vector_type(4))) float f32x4;

// Panel layout for B operands (K=2048): block (n>>4, k>>5) of [16][32] bf16,
// 512 elems per block, 64 k-blocks per n-block row.
// A wave's MFMA B-fragment = one dense 1KB region -> perfectly coalesced.
__device__ __forceinline__ size_t poff(int n, int k) {
  return ((size_t)((n >> 4) * 64 + (k >> 5)) << 9) + (size_t)((n & 15) * 32 + (k & 31));
}

__device__ __forceinline__ void gload16(const unsigned short* g, unsigned short* l) {
  __builtin_amdgcn_global_load_lds(
      (const __attribute__((address_space(1))) void*)(const void*)g,
      (__attribute__((address_space(3))) void*)(void*)l,
      16, 0, 0);
}

// ---------- fp32 -> bf16 convert (vectorized) ----------
__global__ void cvt_bf16(const float* __restrict__ in, unsigned short* __restrict__ outp) {
  size_t i = ((size_t)blockIdx.x * 256 + threadIdx.x) * 4;
  float4 f = *(const float4*)(in + i);
  ushort4 u;
  u.x = f2bf(f.x); u.y = f2bf(f.y); u.z = f2bf(f.z); u.w = f2bf(f.w);
  *(ushort4*)(outp + i) = u;
}

// ---------- row-major f32 [n][k] -> bf16 PANEL, z-batched over 2 ----------
__global__ void panelize_cvt2(const float* __restrict__ in0, unsigned short* __restrict__ out0,
                              const float* __restrict__ in1, unsigned short* __restrict__ out1) {
  const float* in = blockIdx.z ? in1 : in0;
  unsigned short* op = blockIdx.z ? out1 : out0;
  const int n = blockIdx.x * 16 + (threadIdx.x >> 4);
  const int k = blockIdx.y * 128 + (threadIdx.x & 15) * 8;
  float4 f0 = *(const float4*)(in + (size_t)n * Dc + k);
  float4 f1 = *(const float4*)(in + (size_t)n * Dc + k + 4);
  bf16x8 u;
  u[0] = (short)f2bf(f0.x); u[1] = (short)f2bf(f0.y);
  u[2] = (short)f2bf(f0.z); u[3] = (short)f2bf(f0.w);
  u[4] = (short)f2bf(f1.x); u[5] = (short)f2bf(f1.y);
  u[6] = (short)f2bf(f1.z); u[7] = (short)f2bf(f1.w);
  *(bf16x8*)(op + poff(n, k)) = u;
}

// ---------- W [k][n] f32 -> W^T bf16; z 0,1 row-major out, z 2,3 PANEL out ----
__global__ void transpose_mix4(const float* __restrict__ W0, unsigned short* __restrict__ T0,
                               const float* __restrict__ W1, unsigned short* __restrict__ T1,
                               const float* __restrict__ W2, unsigned short* __restrict__ T2,
                               const float* __restrict__ W3, unsigned short* __restrict__ T3) {
  const float* W; unsigned short* Wt; bool pan;
  switch (blockIdx.z) {
    case 0: W = W0; Wt = T0; pan = false; break;
    case 1: W = W1; Wt = T1; pan = false; break;
    case 2: W = W2; Wt = T2; pan = true; break;
    default: W = W3; Wt = T3; pan = true; break;
  }
  __shared__ float tile[32][33];
  int n0 = blockIdx.x * 32, k0 = blockIdx.y * 32;
  int tx = threadIdx.x & 31, ty = threadIdx.x >> 5;  // ty: 0..7
#pragma unroll
  for (int i = 0; i < 4; ++i)
    tile[ty + 8 * i][tx] = W[(size_t)(k0 + ty + 8 * i) * Dc + n0 + tx];
  __syncthreads();
#pragma unroll
  for (int i = 0; i < 4; ++i) {
    const int n = n0 + ty + 8 * i, k = k0 + tx;
    unsigned short v = f2bf(tile[tx][ty + 8 * i]);
    if (pan) Wt[poff(n, k)] = v;
    else     Wt[(size_t)n * Dc + k] = v;
  }
}

// ============================================================================
// GEMM, A in LDS ring-4 / B register-direct from HBM PANELS:
//   C[M,N] = A[M,K](bf16 row-major, lda) * Bt[N,K](bf16 panel)^T
// K hardcoded 2048, BK=32 K-tiles.
//  - A: LDS ring-4 (4 x BM x 32 slabs), staged 3 tiles ahead via
//    global_load_lds; XOR swizzle (source-side; folded into reads; 0 confl).
//  - B: NO LDS. Wave loads its NI fragments as dense 1KB dwordx4 from the
//    panel layout, double-buffered one K-tile ahead in registers (named
//    bufs, unroll-by-2). LDS traffic/tile: 128KB -> 80KB: cap 62% -> ~97%.
//  - vmcnt ledger at end-of-tile wait (FIFO): A(v+1)x2 oldest, A(v+2)x2,
//    B(v+1)x4, A(v+3)x2 = 10 outstanding -> vmcnt(8) drains exactly A(v+1),
//    independent of compiler's intra-tile load order. bCur waits are
//    compiler-inserted (register deps). One barrier per tile (ring-4 slot
//    reuse safe: each wave's reads of a slot complete before its MFMAs,
//    which precede the barrier after which the slot is re-staged).
// EPI: 0 = fp32 store, 1 = bf16 store,
//      3 = fused QKV (N=6144): seg0->exp->C0, seg1->exp->C1, seg2->C2
//      4 = bf16 PANEL store (weight-product output, consumed as B later)
// z-batch: blockIdx.y==1 switches to (A1,B1,C1a).
// ============================================================================
template <int EPI, int WMw, int WNw, int MI, int NI>
__global__ __launch_bounds__(WMw * WNw * 64, 2) void gemmB(
    const unsigned short* __restrict__ A0, const unsigned short* __restrict__ B0,
    void* __restrict__ C0, void* __restrict__ C1, void* __restrict__ C2,
    const unsigned short* __restrict__ A1, const unsigned short* __restrict__ B1,
    void* __restrict__ C1a,
    int M, int N, int lda, int ldc, float eoff) {
  constexpr int K = 2048;
  constexpr int NT = K / 32;                 // 64 K-tiles
  constexpr int THREADS = WMw * WNw * 64;
  constexpr int BM = WMw * MI * 16;
  constexpr int BN = WNw * NI * 16;
  constexpr int ASLAB = BM * 32;             // elems per A K-slab
  constexpr int SROWS = THREADS / 4;         // rows staged per gload pass
  constexpr int APASS = BM / SROWS;
  static_assert(BM % SROWS == 0, "staging geometry");
  static_assert(NI == 4, "vmcnt ledger assumes 4 B loads/tile");
  static_assert(APASS == 2, "vmcnt ledger assumes 2 A gloads/tile");
  extern __shared__ unsigned short lds[];    // 4 * ASLAB elems

  const unsigned short* A = A0;
  const unsigned short* Bt = B0;
  void* Cz = C0;
  if (blockIdx.y) { A = A1; Bt = B1; Cz = C1a; }

  const int tid = threadIdx.x;
  const int lane = tid & 63;
  const int wave = tid >> 6;
  const int wm = wave / WNw;
  const int wn = wave % WNw;

  const int nbn = N / BN;
  const int nwg = (M / BM) * nbn;
  const int bidx = (int)blockIdx.x;
  const int wgid = (bidx & 7) * (nwg >> 3) + (bidx >> 3);  // XCD swizzle (nwg%8==0)
  const int bm = wgid / nbn;
  const int bn = wgid % nbn;

  // ---- A staging: slab = BM rows x 32 bf16 (64B rows), APASS gloads/slab
  const int srow = tid >> 2;                    // 0..SROWS-1
  const int scolL = (tid & 3) << 3;             // linear LDS col (elems)
  const int scolG = scolL ^ ((srow & 6) << 2);  // pre-swizzled global source col
  const unsigned short* gA = A + (size_t)(bm * BM + srow) * lda + scolG;
  const int sstage = srow * 32 + scolL;         // LDS elem offset (linear dest)
  const size_t arstep = (size_t)SROWS * lda;

  // ---- A fragment read offsets (swizzle folded per-lane)
  const int fr = lane & 15;
  const int fko = ((lane >> 4) << 3) ^ ((lane & 6) << 2);
  const int aoff = (wm * MI * 16 + fr) * 32 + fko;            // + mi*512

  // ---- B panel base: fragment (ni, kt) at gBp + ni*32768 + kt*512
  const int bcol = ((EPI == 3) ? (bn & 7) : bn) * BN + wn * (NI * 16);
  const unsigned short* gBp = Bt
      + ((EPI == 3) ? (size_t)(bn >> 3) * ((size_t)Dc * Dc) : 0)
      + ((size_t)(bcol >> 4) << 15)
      + (size_t)(fr * 32 + ((lane >> 4) << 3));

  f32x4 acc[MI][NI] = {};
  bf16x8 bA_[NI], bB_[NI];

  // ---- prologue: stage A tiles 0,1,2 (6 gloads); load B tile 0 into regs
#pragma unroll
  for (int t = 0; t < 3; ++t)
#pragma unroll
    for (int p = 0; p < APASS; ++p)
      gload16(gA + t * 32 + p * arstep, lds + t * ASLAB + sstage + p * SROWS * 32);
#pragma unroll
  for (int ni = 0; ni < NI; ++ni)
    bA_[ni] = *(const bf16x8*)(gBp + ((size_t)ni << 15));
  asm volatile("s_waitcnt vmcnt(8)" ::: "memory");  // A(0) landed
  __builtin_amdgcn_s_barrier();

#define TB(V, BC, BN_)                                                          \
  {                                                                             \
    const int rb = ((V) & 3) * ASLAB;                                           \
    const int wb = (((V) + 3) & 3) * ASLAB;                                     \
    const int tb = ((V) + 1) & (NT - 1);                                        \
    const int ta = ((V) + 3) & (NT - 1);                                        \
    bf16x8 af[MI];                                                              \
    _Pragma("unroll")                                                           \
    for (int mi = 0; mi < MI; ++mi)                                             \
      af[mi] = *(const bf16x8*)(lds + rb + aoff + mi * 512);                    \
    _Pragma("unroll")                                                           \
    for (int ni = 0; ni < NI; ++ni)                                             \
      BN_[ni] = *(const bf16x8*)(gBp + ((size_t)ni << 15) + tb * 512);          \
    _Pragma("unroll")                                                           \
    for (int p = 0; p < APASS; ++p)                                             \
      gload16(gA + ta * 32 + p * arstep, lds + wb + sstage + p * SROWS * 32);   \
    __builtin_amdgcn_s_setprio(1);                                              \
    _Pragma("unroll")                                                           \
    for (int mi = 0; mi < MI; ++mi)                                             \
      _Pragma("unroll")                                                         \
      for (int ni = 0; ni < NI; ++ni)                                           \
        acc[mi][ni] = __builtin_amdgcn_mfma_f32_16x16x32_bf16(                  \
            af[mi], BC[ni], acc[mi][ni], 0, 0, 0);                              \
    __builtin_amdgcn_s_setprio(0);                                              \
    asm volatile("s_waitcnt vmcnt(8)" ::: "memory"); /* A(v+1) landed */        \
    __builtin_amdgcn_s_barrier();                                               \
  }

  for (int v = 0; v < NT; v += 2) {
    TB(v, bA_, bB_)
    TB(v + 1, bB_, bA_)
  }
#undef TB

  // ---- epilogue
  const int fq = lane >> 4;
  const int crow = bm * BM + wm * (MI * 16);
  if constexpr (EPI == 3) {
    const int seg = bn >> 3;  // 0:Q 1:K 2:V   (BN=256, 8 col-blocks/segment)
    unsigned short* outp = (unsigned short*)(seg == 0 ? C0 : (seg == 1 ? C1 : C2));
    const int ccol = (bn & 7) * BN + wn * (NI * 16) + fr;
#pragma unroll
    for (int mi = 0; mi < MI; ++mi)
#pragma unroll
      for (int ni = 0; ni < NI; ++ni)
#pragma unroll
        for (int ii = 0; ii < 4; ++ii) {
          const int r = crow + mi * 16 + fq * 4 + ii;
          const int c = ccol + ni * 16;
          float vv = acc[mi][ni][ii];
          if (seg < 2) vv = __expf(vv + eoff);
          outp[(size_t)r * ldc + c] = f2bf(vv);
        }
  } else if constexpr (EPI == 4) {
    unsigned short* outp = (unsigned short*)Cz;
    const int ccol = bn * BN + wn * (NI * 16) + fr;
#pragma unroll
    for (int mi = 0; mi < MI; ++mi)
#pragma unroll
      for (int ni = 0; ni < NI; ++ni)
#pragma unroll
        for (int ii = 0; ii < 4; ++ii) {
          const int r = crow + mi * 16 + fq * 4 + ii;
          const int c = ccol + ni * 16;
          outp[poff(r, c)] = f2bf(acc[mi][ni][ii]);
        }
  } else {
    const int ccol = bn * BN + wn * (NI * 16) + fr;
#pragma unroll
    for (int mi = 0; mi < MI; ++mi)
#pragma unroll
      for (int ni = 0; ni < NI; ++ni)
#pragma unroll
        for (int ii = 0; ii < 4; ++ii) {
          const int r = crow + mi * 16 + fq * 4 + ii;
          const int c = ccol + ni * 16;
          const size_t idx = (size_t)r * ldc + c;
          float vv = acc[mi][ni][ii];
          if (EPI == 0) ((float*)Cz)[idx] = vv;
          else          ((unsigned short*)Cz)[idx] = f2bf(vv);
        }
  }
}

// ---------- fused dot + chunk-sum: per (bh, chunk) block ----------
__global__ void dot_chunks(const unsigned short* __restrict__ qp,
                           const unsigned short* __restrict__ kp,
                           const unsigned short* __restrict__ v,
                           float* __restrict__ dotb,
                           float* __restrict__ chks) {
  __shared__ float dt[CHUNK];
  const int bid = blockIdx.x;          // bh*NCHUNK + c
  const int c = bid & (NCHUNK - 1);
  const int bh = bid >> 5;
  const int b = bh >> 4, h = bh & 15;
  const int tid = threadIdx.x;         // 256
  const int lane = tid & 63, wv = tid >> 6;
  const int qw = lane >> 4, j = lane & 15;
  const int t0 = c * CHUNK;

#pragma unroll
  for (int pass = 0; pass < 8; ++pass) {
    const int tl = pass * 16 + wv * 4 + qw;   // 0..127
    const int t = t0 + tl;
    const size_t base = ((size_t)(b * Tc + t)) * Dc + h * HDc + j * 8;
    bf16x8 q = *(const bf16x8*)(qp + base);
    bf16x8 k = *(const bf16x8*)(kp + base);
    float p = 0.f;
#pragma unroll
    for (int i = 0; i < 8; ++i)
      p += bf2f((unsigned short)q[i]) * bf2f((unsigned short)k[i]);
#pragma unroll
    for (int m = 8; m; m >>= 1) p += __shfl_xor(p, m);
    if (j == 0) {
      dt[tl] = p;
      dotb[(size_t)bh * Tc + t] = p;
    }
  }
  __syncthreads();
  if (tid < HDc) {
    const int d = tid;
    const unsigned short* vp = v + ((size_t)(b * Tc + t0)) * Dc + h * HDc + d;
    float acc = 0.f;
    for (int t = 0; t < CHUNK; ++t)
      acc += dt[t] * bf2f(vp[(size_t)t * Dc]);
    chks[(size_t)bid * HDc + d] = acc;
  }
}

// ---------- chunked scan: pass 2 (exclusive scan of chunk sums) ----------
__global__ void scan_offsets(float* __restrict__ chks) {
  int bh = blockIdx.x;
  int d = threadIdx.x;
  float run = 0.f;
  for (int c = 0; c < NCHUNK; ++c) {
    size_t idx = ((size_t)bh * NCHUNK + c) * HDc + d;
    float tmp = chks[idx];
    chks[idx] = run;
    run += tmp;
  }
}

// ---------- chunked scan: pass 3 (final prefix + divide by kp, bf16 out) ----------
__global__ void scan_final(const float* __restrict__ dotb,
                           const unsigned short* __restrict__ v,
                           const unsigned short* __restrict__ kp,
                           const float* __restrict__ chks,
                           unsigned short* __restrict__ attn) {
  int bid = blockIdx.x;
  int c = bid % NCHUNK, bh = bid / NCHUNK;
  int b = bh / Hc, h = bh % Hc;
  int d = threadIdx.x;
  const float* dp = dotb + (size_t)bh * Tc + c * CHUNK;
  size_t base = ((size_t)(b * Tc + c * CHUNK)) * Dc + h * HDc + d;
  float acc = chks[(size_t)bid * HDc + d];
  for (int t = 0; t < CHUNK; ++t) {
    size_t idx = base + (size_t)t * Dc;
    acc += dp[t] * bf2f(v[idx]);
    attn[idx] = f2bf(acc / bf2f(kp[idx]));
  }
}

// ---------- launch ----------
extern "C" void kernel_launch(void* const* d_in, const int* in_sizes, int n_in,
                              void* d_out, int out_size, void* d_ws, size_t ws_size,
                              hipStream_t stream) {
  const float* hs = (const float*)d_in[0];
  const float* Wq = (const float*)d_in[1];
  const float* Wk = (const float*)d_in[2];
  const float* Wv = (const float*)d_in[3];
  const float* Wo = (const float*)d_in[4];
  const float* Fq = (const float*)d_in[5];
  const float* Fk = (const float*)d_in[6];
  float* out = (float*)d_out;

  const size_t MD = (size_t)Mrows * Dc;  // 16,777,216
  const size_t DD = (size_t)Dc * Dc;     // 4,194,304 (MD == 4*DD)

  char* w = (char*)d_ws;
  size_t off = 0;
  auto take = [&](size_t bytes) -> void* {
    void* r = w + off;
    off += (bytes + 255) & ~(size_t)255;
    return r;
  };

  unsigned short* hs_bf = (unsigned short*)take(MD * 2);  // reused as attnbf
  unsigned short* wqP  = (unsigned short*)take(DD * 2);   // these 4 reused as Qp
  unsigned short* wtfq = (unsigned short*)take(DD * 2);
  unsigned short* wkP  = (unsigned short*)take(DD * 2);
  unsigned short* wtfk = (unsigned short*)take(DD * 2);
  unsigned short* wcat = (unsigned short*)take(3 * DD * 2);  // panels [WqfT|WkfT|WvT]
  unsigned short* woP  = (unsigned short*)take(DD * 2);      // Wo^T panel
  unsigned short* Kp   = (unsigned short*)take(MD * 2);
  unsigned short* Vbf  = (unsigned short*)take(MD * 2);
  float* dotb = (float*)take((size_t)Bc * Hc * Tc * 4);
  float* chks = (float*)take((size_t)Bc * Hc * NCHUNK * HDc * 4);

  // aliases (stream-ordered reuse)
  unsigned short* Qp = wqP;          // over the 4 dead weight buffers (4*DD == MD)
  unsigned short* attnbf = hs_bf;    // hs_bf dead after fused QKV GEMM

  const float OFF = (float)(-0.5 * log(2048.0) + 1e-6);

  // allow dynamic LDS (defensive; ignore errors)
  (void)hipFuncSetAttribute((const void*)gemmB<0, 2, 4, 8, 4>, hipFuncAttributeMaxDynamicSharedMemorySize, 65536);
  (void)hipFuncSetAttribute((const void*)gemmB<3, 2, 4, 8, 4>, hipFuncAttributeMaxDynamicSharedMemorySize, 65536);
  (void)hipFuncSetAttribute((const void*)gemmB<4, 2, 2, 4, 4>, hipFuncAttributeMaxDynamicSharedMemorySize, 32768);

  // 1) convert activations; panelize Wq, Wk (B operands of the weight pair)
  cvt_bf16<<<(int)(MD / 1024), 256, 0, stream>>>(hs, hs_bf);
  panelize_cvt2<<<dim3(Dc / 16, Dc / 128, 2), 256, 0, stream>>>(Wq, wqP, Wk, wkP);

  // 2) Fq^T, Fk^T row-major (A operands); Wv^T, Wo^T panels (B operands)
  transpose_mix4<<<dim3(Dc / 32, Dc / 32, 4), 256, 0, stream>>>(
      Fq, wtfq, Fk, wtfk, Wv, wcat + 2 * DD, Wo, woP);

  // 3) weight products -> PANEL output (consumed as QKV's B):
  //    wcat[0:DD) = panel((Wq@Fq)^T); wcat[DD:2DD) = panel((Wk@Fk)^T)
  gemmB<4, 2, 2, 4, 4><<<dim3(256, 2), 256, 32768, stream>>>(
      wtfq, wqP, wcat, nullptr, nullptr,
      wtfk, wkP, wcat + DD,
      2048, 2048, 2048, 2048, 0.f);

  // 4) fused QKV GEMM: hs @ [Wqf|Wkf|Wv], epilogue exp/exp/plain -> Qp,Kp,Vbf
  const int fblocks = (Mrows / 256) * (6144 / 256);  // 768
  gemmB<3, 2, 4, 8, 4><<<fblocks, 512, 65536, stream>>>(
      hs_bf, wcat, Qp, Kp, Vbf, nullptr, nullptr, nullptr,
      Mrows, 6144, Dc, Dc, OFF);

  // 5) fused per-position dot + chunk sums
  dot_chunks<<<Bc * Hc * NCHUNK, 256, 0, stream>>>(Qp, Kp, Vbf, dotb, chks);

  // 6) exclusive scan of chunk sums + final prefix/divide
  scan_offsets<<<Bc * Hc, 128, 0, stream>>>(chks);
  scan_final<<<Bc * Hc * NCHUNK, 128, 0, stream>>>(dotb, Vbf, Kp, chks, attnbf);

  // 7) output projection (fp32 out)
  const int gblocks = (Mrows / 256) * (Dc / 256);  // 256
  gemmB<0, 2, 4, 8, 4><<<gblocks, 512, 65536, stream>>>(
      attnbf, woP, out, nullptr, nullptr, nullptr, nullptr, nullptr,
      Mrows, Dc, Dc, Dc, 0.f);
}

// Round 10
// 419.823 us; speedup vs baseline: 1.2443x; 1.0738x over previous
//
#include <hip/hip_runtime.h>
#include <hip/hip_bf16.h>
#include <cmath>

// Problem constants
constexpr int Bc = 2, Tc = 4096, Dc = 2048, Hc = 16, HDc = 128;
constexpr int Mrows = Bc * Tc;            // 8192
constexpr int NCHUNK = 32, CHUNK = 128;   // T = NCHUNK * CHUNK
constexpr int BHT = Bc * Hc * Tc;         // 131072

// ---------- small helpers ----------
__device__ __forceinline__ unsigned short f2bf(float x) {
  union { float f; unsigned int u; } v; v.f = x;
  unsigned int r = v.u + 0x7FFFu + ((v.u >> 16) & 1u);  // RNE
  return (unsigned short)(r >> 16);
}
__device__ __forceinline__ float bf2f(unsigned short u) {
  union { unsigned int i; float f; } v; v.i = ((unsigned int)u) << 16;
  return v.f;
}

typedef __attribute__((ext_vector_type(8))) short bf16x8;
typedef __attribute__((ext_vector_type(4))) float f32x4;

__device__ __forceinline__ void gload16(const unsigned short* g, unsigned short* l) {
  __builtin_amdgcn_global_load_lds(
      (const __attribute__((address_space(1))) void*)(const void*)g,
      (__attribute__((address_space(3))) void*)(void*)l,
      16, 0, 0);
}

// ---------- fp32 -> bf16 convert ----------
__global__ void cvt_bf16(const float* __restrict__ in, unsigned short* __restrict__ outp) {
  size_t i = ((size_t)blockIdx.x * 256 + threadIdx.x) * 4;
  float4 f = *(const float4*)(in + i);
  ushort4 u;
  u.x = f2bf(f.x); u.y = f2bf(f.y); u.z = f2bf(f.z); u.w = f2bf(f.w);
  *(ushort4*)(outp + i) = u;
}

__global__ void cvt_bf16_2(const float* __restrict__ in0, unsigned short* __restrict__ out0,
                           const float* __restrict__ in1, unsigned short* __restrict__ out1) {
  const float* in = blockIdx.y ? in1 : in0;
  unsigned short* op = blockIdx.y ? out1 : out0;
  size_t i = ((size_t)blockIdx.x * 256 + threadIdx.x) * 4;
  float4 f = *(const float4*)(in + i);
  ushort4 u;
  u.x = f2bf(f.x); u.y = f2bf(f.y); u.z = f2bf(f.z); u.w = f2bf(f.w);
  *(ushort4*)(op + i) = u;
}

// ---------- dst += src (bf16, vectorized) ----------
__global__ void add_bf16(unsigned short* __restrict__ dst, const unsigned short* __restrict__ src) {
  size_t i = ((size_t)blockIdx.x * 256 + threadIdx.x) * 8;
  bf16x8 a = *(const bf16x8*)(dst + i);
  bf16x8 b = *(const bf16x8*)(src + i);
#pragma unroll
  for (int j = 0; j < 8; ++j)
    a[j] = (short)f2bf(bf2f((unsigned short)a[j]) + bf2f((unsigned short)b[j]));
  *(bf16x8*)(dst + i) = a;
}

// ---------- W [K][N] fp32 -> Wt [N][K] bf16, z-batched over 4 matrices ----------
__global__ void transpose_cvt4(const float* __restrict__ W0, unsigned short* __restrict__ T0,
                               const float* __restrict__ W1, unsigned short* __restrict__ T1,
                               const float* __restrict__ W2, unsigned short* __restrict__ T2,
                               const float* __restrict__ W3, unsigned short* __restrict__ T3) {
  const float* W; unsigned short* Wt;
  switch (blockIdx.z) {
    case 0: W = W0; Wt = T0; break;
    case 1: W = W1; Wt = T1; break;
    case 2: W = W2; Wt = T2; break;
    default: W = W3; Wt = T3; break;
  }
  __shared__ float tile[32][33];
  int n0 = blockIdx.x * 32, k0 = blockIdx.y * 32;
  int tx = threadIdx.x & 31, ty = threadIdx.x >> 5;  // ty: 0..7
#pragma unroll
  for (int i = 0; i < 4; ++i)
    tile[ty + 8 * i][tx] = W[(size_t)(k0 + ty + 8 * i) * Dc + n0 + tx];
  __syncthreads();
#pragma unroll
  for (int i = 0; i < 4; ++i)
    Wt[(size_t)(n0 + ty + 8 * i) * Dc + k0 + tx] = f2bf(tile[tx][ty + 8 * i]);
}

// ============================================================================
// Barrier-light ring-4 GEMM (R7 structure, 49.5% MfmaUtil champion):
//   C[M,N] = A[M,K](bf16, lda) * Bt[N,K](bf16)^T, K hardcoded 2048, BK=32.
// LDS ring of 4 (A-slab + B-slab) buffers, staged 3 tiles ahead via
// global_load_lds. ONE vmcnt(8) + ONE s_barrier per K-tile; compiler emits
// fine-grained lgkmcnt so ds_read ∥ MFMA; waves drift, setprio arbitrates.
// XOR bank-conflict swizzle (0 conflicts verified): pre-swizzled global
// source for staging (LDS dest linear) + swizzle folded into per-lane reads.
// EPI: 0 = fp32 store, 1 = bf16 store,
//      5 = fused SKV (N=6144): seg0 = S: exp(acc+2*eoff) row-reduced over the
//          wave's 64 cols -> per-head partial dots into C0 (dotP[2][BH*T]),
//          NO C store; seg1 = exp(acc+eoff)->C1 (K'); seg2 = plain->C2 (V).
// z-batch: blockIdx.y==1 switches to (A1,B1,C1a) (weight-pair use).
// ============================================================================
template <int EPI, int WMw, int WNw, int MI, int NI>
__global__ __launch_bounds__(WMw * WNw * 64, 2) void gemmL(
    const unsigned short* __restrict__ A0, const unsigned short* __restrict__ B0,
    void* __restrict__ C0, void* __restrict__ C1, void* __restrict__ C2,
    const unsigned short* __restrict__ A1, const unsigned short* __restrict__ B1,
    void* __restrict__ C1a,
    int M, int N, int lda, int ldc, float eoff) {
  constexpr int K = 2048;
  constexpr int NT = K / 32;                 // 64 K-tiles
  constexpr int THREADS = WMw * WNw * 64;
  constexpr int BM = WMw * MI * 16;
  constexpr int BN = WNw * NI * 16;
  constexpr int ASLAB = BM * 32;             // elems per A K-slab
  constexpr int BSLAB = BN * 32;
  constexpr int BUF = ASLAB + BSLAB;
  constexpr int SROWS = THREADS / 4;         // rows staged per gload pass
  static_assert(2 * SROWS == BM && BM == BN, "staging geometry");
  extern __shared__ unsigned short lds[];    // 4 * BUF elems

  const unsigned short* A = A0;
  const unsigned short* Bt = B0;
  void* Cz = C0;
  if (blockIdx.y) { A = A1; Bt = B1; Cz = C1a; }

  const int tid = threadIdx.x;
  const int lane = tid & 63;
  const int wave = tid >> 6;
  const int wm = wave / WNw;
  const int wn = wave % WNw;

  const int nbn = N / BN;
  const int nwg = (M / BM) * nbn;
  const int bidx = (int)blockIdx.x;
  const int wgid = (bidx & 7) * (nwg >> 3) + (bidx >> 3);  // XCD swizzle (nwg%8==0)
  const int bm = wgid / nbn;
  const int bn = wgid % nbn;

  // ---- staging: slab = BM rows x 32 bf16 (64B rows), 2 gloads per slab
  const int srow = tid >> 2;                    // 0..SROWS-1
  const int scolL = (tid & 3) << 3;             // linear LDS col (elems)
  const int scolG = scolL ^ ((srow & 6) << 2);  // pre-swizzled global source col
  const unsigned short* gA = A + (size_t)(bm * BM + srow) * lda + scolG;
  const unsigned short* gB = Bt + (size_t)(bn * BN + srow) * K + scolG;
  const int sstage = srow * 32 + scolL;         // LDS elem offset (linear dest)
  const size_t arstep = (size_t)SROWS * lda;
  const size_t brstep = (size_t)SROWS * K;

  // ---- fragment read offsets (swizzle folded per-lane)
  const int fr = lane & 15;
  const int fko = ((lane >> 4) << 3) ^ ((lane & 6) << 2);
  const int aoff = (wm * MI * 16 + fr) * 32 + fko;            // + mi*512
  const int boff = ASLAB + (wn * NI * 16 + fr) * 32 + fko;    // + ni*512

  f32x4 acc[MI][NI] = {};

  // ---- prologue: stage tiles 0,1,2 into slots 0,1,2 (12 gloads)
#pragma unroll
  for (int t = 0; t < 3; ++t) {
    const unsigned short* sA = gA + t * 32;
    const unsigned short* sB = gB + t * 32;
    unsigned short* dst = lds + t * BUF;
    gload16(sA,          dst + sstage);
    gload16(sA + arstep, dst + sstage + SROWS * 32);
    gload16(sB,          dst + ASLAB + sstage);
    gload16(sB + brstep, dst + ASLAB + sstage + SROWS * 32);
  }
  asm volatile("s_waitcnt vmcnt(8)" ::: "memory");  // tile 0 landed
  __builtin_amdgcn_s_barrier();

  for (int v = 0; v < NT; ++v) {
    const int rb = (v & 3) * BUF;            // read slot
    const int wb = ((v + 3) & 3) * BUF;      // stage slot (tile v+3)
    const int tn = (v + 3) & (NT - 1);       // wrap-stage near tail: harmless
    const unsigned short* srcA = gA + tn * 32;
    const unsigned short* srcB = gB + tn * 32;

    // ds_reads for tile v (compiler inserts fine-grained lgkmcnt before MFMA)
    bf16x8 af[MI], bfv[NI];
#pragma unroll
    for (int mi = 0; mi < MI; ++mi)
      af[mi] = *(const bf16x8*)(lds + rb + aoff + mi * 512);
#pragma unroll
    for (int ni = 0; ni < NI; ++ni)
      bfv[ni] = *(const bf16x8*)(lds + rb + boff + ni * 512);

    // stage tile v+3
    gload16(srcA,          lds + wb + sstage);
    gload16(srcA + arstep, lds + wb + sstage + SROWS * 32);
    gload16(srcB,          lds + wb + ASLAB + sstage);
    gload16(srcB + brstep, lds + wb + ASLAB + sstage + SROWS * 32);

    // MFMA cluster
    __builtin_amdgcn_s_setprio(1);
#pragma unroll
    for (int mi = 0; mi < MI; ++mi)
#pragma unroll
      for (int ni = 0; ni < NI; ++ni)
        acc[mi][ni] = __builtin_amdgcn_mfma_f32_16x16x32_bf16(af[mi], bfv[ni], acc[mi][ni], 0, 0, 0);
    __builtin_amdgcn_s_setprio(0);

    // one counted wait + one barrier per tile: tile v+1 landed for all waves
    asm volatile("s_waitcnt vmcnt(8)" ::: "memory");
    __builtin_amdgcn_s_barrier();
  }

  // ---- epilogue
  const int fq = lane >> 4;
  const int crow = bm * BM + wm * (MI * 16);
  if constexpr (EPI == 5) {
    const int seg = bn >> 3;  // 0:S(dot) 1:K' 2:V   (BN=256, 8 col-blocks/seg)
    if (seg == 0) {
      // row-sum of exp(S + 2*eoff) over this wave's 64 cols
      float s2[MI][4];
#pragma unroll
      for (int mi = 0; mi < MI; ++mi)
#pragma unroll
        for (int ii = 0; ii < 4; ++ii) {
          float t = 0.f;
#pragma unroll
          for (int ni = 0; ni < NI; ++ni)
            t += __expf(acc[mi][ni][ii] + 2.f * eoff);
          s2[mi][ii] = t;
        }
      // reduce over fr (lane bits 0..3); all 16 lanes end with the full sum
#pragma unroll
      for (int m = 1; m < 16; m <<= 1)
#pragma unroll
        for (int mi = 0; mi < MI; ++mi)
#pragma unroll
          for (int ii = 0; ii < 4; ++ii)
            s2[mi][ii] += __shfl_xor(s2[mi][ii], m);
      // head & partial-id; each lane stores 2 of the wave's 128 row-sums
      const int h = (bn & 7) * 2 + (wn >> 1);
      const int part = wn & 1;
      float* dp = (float*)C0 + (size_t)part * BHT;
#pragma unroll
      for (int u = 0; u < 2; ++u) {
        const int idx = fr * 2 + u;            // 0..31
        const int mi = idx >> 2, ii = idx & 3;
        const int r = crow + mi * 16 + fq * 4 + ii;
        const int b = r >> 12, t = r & (Tc - 1);
        dp[((size_t)(b * Hc + h)) * Tc + t] = s2[mi][ii];
      }
    } else {
      unsigned short* outp = (unsigned short*)(seg == 1 ? C1 : C2);
      const int ccol = (bn & 7) * BN + wn * (NI * 16) + fr;
#pragma unroll
      for (int mi = 0; mi < MI; ++mi)
#pragma unroll
        for (int ni = 0; ni < NI; ++ni)
#pragma unroll
          for (int ii = 0; ii < 4; ++ii) {
            const int r = crow + mi * 16 + fq * 4 + ii;
            const int c = ccol + ni * 16;
            float vv = acc[mi][ni][ii];
            if (seg == 1) vv = __expf(vv + eoff);
            outp[(size_t)r * ldc + c] = f2bf(vv);
          }
    }
  } else {
    const int ccol = bn * BN + wn * (NI * 16) + fr;
#pragma unroll
    for (int mi = 0; mi < MI; ++mi)
#pragma unroll
      for (int ni = 0; ni < NI; ++ni)
#pragma unroll
        for (int ii = 0; ii < 4; ++ii) {
          const int r = crow + mi * 16 + fq * 4 + ii;
          const int c = ccol + ni * 16;
          const size_t idx = (size_t)r * ldc + c;
          float vv = acc[mi][ni][ii];
          if (EPI == 0) ((float*)Cz)[idx] = vv;
          else          ((unsigned short*)Cz)[idx] = f2bf(vv);
        }
  }
}

// ---------- combine dot partials + per-chunk V sums ----------
__global__ void scan_chunks2(const float* __restrict__ dotP,
                             const unsigned short* __restrict__ v,
                             float* __restrict__ dotb,
                             float* __restrict__ chks) {
  __shared__ float dt[CHUNK];
  const int bid = blockIdx.x;          // bh*NCHUNK + c
  const int c = bid & (NCHUNK - 1);
  const int bh = bid >> 5;
  const int b = bh >> 4, h = bh & 15;
  const int d = threadIdx.x;           // 128
  const int t0 = c * CHUNK;

  const size_t di = (size_t)bh * Tc + t0 + d;
  float dv = dotP[di] + dotP[(size_t)BHT + di];
  dt[d] = dv;
  dotb[di] = dv;
  __syncthreads();

  const unsigned short* vp = v + ((size_t)(b * Tc + t0)) * Dc + h * HDc + d;
  float acc = 0.f;
  for (int t = 0; t < CHUNK; ++t)
    acc += dt[t] * bf2f(vp[(size_t)t * Dc]);
  chks[(size_t)bid * HDc + d] = acc;
}

// ---------- chunked scan: pass 2 (exclusive scan of chunk sums) ----------
__global__ void scan_offsets(float* __restrict__ chks) {
  int bh = blockIdx.x;
  int d = threadIdx.x;
  float run = 0.f;
  for (int c = 0; c < NCHUNK; ++c) {
    size_t idx = ((size_t)bh * NCHUNK + c) * HDc + d;
    float tmp = chks[idx];
    chks[idx] = run;
    run += tmp;
  }
}

// ---------- chunked scan: pass 3 (final prefix + divide by kp, bf16 out) ----------
__global__ void scan_final(const float* __restrict__ dotb,
                           const unsigned short* __restrict__ v,
                           const unsigned short* __restrict__ kp,
                           const float* __restrict__ chks,
                           unsigned short* __restrict__ attn) {
  int bid = blockIdx.x;
  int c = bid % NCHUNK, bh = bid / NCHUNK;
  int b = bh / Hc, h = bh % Hc;
  int d = threadIdx.x;
  const float* dp = dotb + (size_t)bh * Tc + c * CHUNK;
  size_t base = ((size_t)(b * Tc + c * CHUNK)) * Dc + h * HDc + d;
  float acc = chks[(size_t)bid * HDc + d];
  for (int t = 0; t < CHUNK; ++t) {
    size_t idx = base + (size_t)t * Dc;
    acc += dp[t] * bf2f(v[idx]);
    attn[idx] = f2bf(acc / bf2f(kp[idx]));
  }
}

// ---------- launch ----------
extern "C" void kernel_launch(void* const* d_in, const int* in_sizes, int n_in,
                              void* d_out, int out_size, void* d_ws, size_t ws_size,
                              hipStream_t stream) {
  const float* hs = (const float*)d_in[0];
  const float* Wq = (const float*)d_in[1];
  const float* Wk = (const float*)d_in[2];
  const float* Wv = (const float*)d_in[3];
  const float* Wo = (const float*)d_in[4];
  const float* Fq = (const float*)d_in[5];
  const float* Fk = (const float*)d_in[6];
  float* out = (float*)d_out;

  const size_t MD = (size_t)Mrows * Dc;  // 16,777,216
  const size_t DD = (size_t)Dc * Dc;     // 4,194,304

  char* w = (char*)d_ws;
  size_t off = 0;
  auto take = [&](size_t bytes) -> void* {
    void* r = w + off;
    off += (bytes + 255) & ~(size_t)255;
    return r;
  };

  unsigned short* hs_bf = (unsigned short*)take(MD * 2);  // reused as attnbf
  unsigned short* wq_bf = (unsigned short*)take(DD * 2);
  unsigned short* wtfq  = (unsigned short*)take(DD * 2);
  unsigned short* wk_bf = (unsigned short*)take(DD * 2);
  unsigned short* wtfk  = (unsigned short*)take(DD * 2);
  unsigned short* wcat  = (unsigned short*)take(3 * DD * 2);  // [Wsum^T|Wkf^T|Wv^T]
  unsigned short* wto   = (unsigned short*)take(DD * 2);
  unsigned short* Kp    = (unsigned short*)take(MD * 2);
  unsigned short* Vbf   = (unsigned short*)take(MD * 2);
  float* dotP = (float*)take((size_t)2 * BHT * 4);            // per-head dot partials
  float* dotb = (float*)take((size_t)BHT * 4);
  float* chks = (float*)take((size_t)Bc * Hc * NCHUNK * HDc * 4);

  // alias (stream-ordered reuse): hs_bf dead after fused SKV GEMM
  unsigned short* attnbf = hs_bf;

  const float OFF = (float)(-0.5 * log(2048.0) + 1e-6);

  // allow dynamic LDS (defensive; ignore errors)
  (void)hipFuncSetAttribute((const void*)gemmL<0, 2, 4, 8, 4>, hipFuncAttributeMaxDynamicSharedMemorySize, 131072);
  (void)hipFuncSetAttribute((const void*)gemmL<5, 2, 4, 8, 4>, hipFuncAttributeMaxDynamicSharedMemorySize, 131072);
  (void)hipFuncSetAttribute((const void*)gemmL<1, 2, 2, 4, 4>, hipFuncAttributeMaxDynamicSharedMemorySize, 65536);

  // 1) convert activations + plain-layout Wq, Wk
  cvt_bf16<<<(int)(MD / 1024), 256, 0, stream>>>(hs, hs_bf);
  cvt_bf16_2<<<dim3((int)(DD / 1024), 2), 256, 0, stream>>>(Wq, wq_bf, Wk, wk_bf);

  // 2) transpose+convert Fq, Fk, Wv, Wo (one z-batched dispatch)
  transpose_cvt4<<<dim3(Dc / 32, Dc / 32, 4), 256, 0, stream>>>(
      Fq, wtfq, Fk, wtfk, Wv, wcat + 2 * DD, Wo, wto);

  // 3) weight products (z-batched, 128^2 tiles, ring-4 = 64KB LDS):
  //    wcat[0:DD) = (Wq@Fq)^T ; wcat[DD:2DD) = (Wk@Fk)^T
  gemmL<1, 2, 2, 4, 4><<<dim3(256, 2), 256, 65536, stream>>>(
      wtfq, wq_bf, wcat, nullptr, nullptr,
      wtfk, wk_bf, wcat + DD,
      2048, 2048, 2048, 2048, 0.f);

  // 3b) Wsum^T = Wqf^T + Wkf^T (in place over wcat[0:DD))
  add_bf16<<<(int)(DD / 2048), 256, 0, stream>>>(wcat, wcat + DD);

  // 4) fused SKV GEMM: hs @ [Wsum|Wkf|Wv] ->
  //    seg0: per-head dot partials (dotP), seg1: K'=exp (Kp), seg2: V (Vbf)
  const int fblocks = (Mrows / 256) * (6144 / 256);  // 768
  gemmL<5, 2, 4, 8, 4><<<fblocks, 512, 131072, stream>>>(
      hs_bf, wcat, dotP, Kp, Vbf, nullptr, nullptr, nullptr,
      Mrows, 6144, Dc, Dc, OFF);

  // 5) combine dot partials + per-chunk V sums
  scan_chunks2<<<Bc * Hc * NCHUNK, 128, 0, stream>>>(dotP, Vbf, dotb, chks);

  // 6) exclusive scan of chunk sums + final prefix/divide
  scan_offsets<<<Bc * Hc, 128, 0, stream>>>(chks);
  scan_final<<<Bc * Hc * NCHUNK, 128, 0, stream>>>(dotb, Vbf, Kp, chks, attnbf);

  // 7) output projection (fp32 out)
  const int gblocks = (Mrows / 256) * (Dc / 256);  // 256
  gemmL<0, 2, 4, 8, 4><<<gblocks, 512, 131072, stream>>>(
      attnbf, wto, out, nullptr, nullptr, nullptr, nullptr, nullptr,
      Mrows, Dc, Dc, Dc, 0.f);
}